// Round 1
// baseline (333.015 us; speedup 1.0000x reference)
//
#include <hip/hip_runtime.h>
#include <hip/hip_bf16.h>
#include <stdint.h>

// ConvNACCell: out[n,co,h,w] = sum_{ci,kh,kw} x[n,ci,h+kh-1,w+kw-1] * W[co,ci,kh,kw]
// W = tanh(W_hat)*sigmoid(M_hat), W_hat/M_hat are [128, 576] with k = ci*9 + kh*3 + kw.
// Implemented as implicit GEMM with mfma_f32_16x16x32_bf16, fp32 accumulate.

#define CH_IN  64
#define CH_OUT 128
#define HW     256
#define NBATCH 16

typedef __attribute__((ext_vector_type(8))) short short8;   // 8 bf16 = 4 VGPR
typedef __attribute__((ext_vector_type(4))) float f32x4;

// RNE fp32 -> bf16 pair packed into u32 (lo = a, hi = b). Inputs are finite.
static __device__ __forceinline__ uint32_t pack_bf16(float a, float b) {
    uint32_t ua = __builtin_bit_cast(uint32_t, a);
    uint32_t ub = __builtin_bit_cast(uint32_t, b);
    ua = (ua + 0x7FFFu + ((ua >> 16) & 1u)) >> 16;
    ub = (ub + 0x7FFFu + ((ub >> 16) & 1u));
    return (ua & 0xFFFFu) | (ub & 0xFFFF0000u);
}

// ---------------------------------------------------------------------------
// Prep: W = tanh(W_hat)*sigmoid(M_hat), stored as bf16 in A-fragment order:
//   frag[t][ms][s][lane] (16B each), t=tap(9), ms=m-slot(8: co tile of 16),
//   s=k-step(2: K=32 each), lane=64.
//   Element j (0..7) of lane's 16B = A[co = ms*16 + (lane&15)]
//                                     [ci = s*32 + (lane>>4)*8 + j]  (tap t)
// Total 9*8*2*64*16 = 147,456 B in d_ws.
// ---------------------------------------------------------------------------
__global__ void __launch_bounds__(256) nac_prep(const float* __restrict__ Wh,
                                                const float* __restrict__ Mh,
                                                uint32_t* __restrict__ Af) {
    int f = blockIdx.x * 256 + threadIdx.x;   // 0..9215
    if (f >= 9 * 8 * 2 * 64) return;
    int lane = f & 63;
    int s    = (f >> 6) & 1;
    int ms   = (f >> 7) & 7;
    int t    = f >> 10;                        // 0..8
    int co   = ms * 16 + (lane & 15);
    int ci0  = s * 32 + ((lane >> 4) << 3);

    uint32_t pk[4];
#pragma unroll
    for (int j2 = 0; j2 < 4; ++j2) {
        int ci = ci0 + 2 * j2;
        int k0 = ci * 9 + t;          // (ci, t)
        int k1 = k0 + 9;              // (ci+1, t)
        float w0 = tanhf(Wh[co * 576 + k0]);
        float m0 = Mh[co * 576 + k0];
        float w1 = tanhf(Wh[co * 576 + k1]);
        float m1 = Mh[co * 576 + k1];
        float v0 = w0 * (1.0f / (1.0f + expf(-m0)));
        float v1 = w1 * (1.0f / (1.0f + expf(-m1)));
        pk[j2] = pack_bf16(v0, v1);
    }
    int fragidx = ((t * 8 + ms) * 2 + s) * 64 + lane;
    reinterpret_cast<uint4*>(Af)[fragidx] = make_uint4(pk[0], pk[1], pk[2], pk[3]);
}

// ---------------------------------------------------------------------------
// Conv: one block = 128 C_out x (2 rows x 64 cols) output tile.
// LDS x-tile: packed bf16 pairs, layout [pg(8)][pp(272)][pj(4)] of u32 where
//   pg = ci/8, pp = r*68 + c (r=0..3 rows h0-1..h0+2, c=0..67 cols w0-1..w0+66),
//   pj holds ci pair (8pg+2pj, 8pg+2pj+1).
// B-fragment for k-step s: one ds_read_b128 at pg = s*4 + (lane>>4),
//   pp = (wn+kh)*68 + lw + kw  -> 8 bf16 with ci = s*32 + (lane>>4)*8 + j.
// ---------------------------------------------------------------------------
__global__ void __launch_bounds__(256) nac_conv(const float* __restrict__ x,
                                                const uint32_t* __restrict__ Af,
                                                float* __restrict__ out) {
    __shared__ uint32_t xl[8 * 272 * 4];   // 34,816 B

    // Bijective XCD-chunked swizzle: 8192 blocks, 8 XCDs, 1024 per chunk.
    unsigned bid = blockIdx.x;
    unsigned idx = (bid & 7u) * 1024u + (bid >> 3);
    int ht = idx & 127;          // h tile (2 rows each)
    int wt = (idx >> 7) & 3;     // w tile (64 cols each)
    int n  = idx >> 9;           // batch
    int h0 = ht * 2;
    int w0 = wt * 64;

    int tid = threadIdx.x;

    // ---- stage x tile (fp32 -> packed bf16) ----
    const float* xn = x + (size_t)n * CH_IN * HW * HW;
    for (int it = 0; it < 9; ++it) {
        int task = tid + it * 256;               // (r, pg, c): 4*8*68 = 2176 tasks
        if (task < 2176) {
            int r   = task / 544;
            int rem = task - r * 544;
            int pg  = rem / 68;
            int c   = rem - pg * 68;
            int hrow = h0 - 1 + r;
            int w    = w0 - 1 + c;
            float v[8];
            if ((unsigned)hrow < 256u && (unsigned)w < 256u) {
                const float* p = xn + ((size_t)(pg * 8) * HW + hrow) * HW + w;
#pragma unroll
                for (int e = 0; e < 8; ++e) v[e] = p[(size_t)e * HW * HW];
            } else {
#pragma unroll
                for (int e = 0; e < 8; ++e) v[e] = 0.0f;
            }
            uint4 wd;
            wd.x = pack_bf16(v[0], v[1]);
            wd.y = pack_bf16(v[2], v[3]);
            wd.z = pack_bf16(v[4], v[5]);
            wd.w = pack_bf16(v[6], v[7]);
            *reinterpret_cast<uint4*>(&xl[(pg * 272 + r * 68 + c) * 4]) = wd;
        }
    }
    __syncthreads();

    // ---- compute ----
    int lane = tid & 63;
    int wv   = tid >> 6;       // wave 0..3
    int wm   = wv >> 1;        // co half: 0 -> co 0..63, 1 -> co 64..127
    int wn   = wv & 1;         // output row within tile (h0 + wn)
    int row4 = lane >> 4;      // 0..3
    int col  = lane & 15;

    f32x4 acc[4][4];
#pragma unroll
    for (int mi = 0; mi < 4; ++mi)
#pragma unroll
        for (int ni = 0; ni < 4; ++ni)
            acc[mi][ni] = (f32x4){0.f, 0.f, 0.f, 0.f};

    const short8* Afr = reinterpret_cast<const short8*>(Af);

    for (int t = 0; t < 9; ++t) {
        int kh = t / 3, kw = t % 3;
        // A fragments for this tap: 8 x 16B coalesced global loads (L2-hot)
        short8 a[2][4];
#pragma unroll
        for (int s = 0; s < 2; ++s)
#pragma unroll
            for (int mi = 0; mi < 4; ++mi)
                a[s][mi] = Afr[((t * 8 + (wm * 4 + mi)) * 2 + s) * 64 + lane];

#pragma unroll
        for (int s = 0; s < 2; ++s) {
            short8 b[4];
#pragma unroll
            for (int ni = 0; ni < 4; ++ni) {
                int pg = s * 4 + row4;
                int pp = (wn + kh) * 68 + ni * 16 + col + kw;
                b[ni] = *reinterpret_cast<const short8*>(&xl[(pg * 272 + pp) * 4]);
            }
#pragma unroll
            for (int mi = 0; mi < 4; ++mi)
#pragma unroll
                for (int ni = 0; ni < 4; ++ni)
                    acc[mi][ni] = __builtin_amdgcn_mfma_f32_16x16x32_bf16(
                        a[s][mi], b[ni], acc[mi][ni], 0, 0, 0);
        }
    }

    // ---- store (C/D layout: col = lane&15, row = (lane>>4)*4 + reg) ----
#pragma unroll
    for (int mi = 0; mi < 4; ++mi) {
#pragma unroll
        for (int reg = 0; reg < 4; ++reg) {
            int co = wm * 64 + mi * 16 + row4 * 4 + reg;
            float* op = out + (((size_t)n * CH_OUT + co) * HW + (h0 + wn)) * HW + w0;
#pragma unroll
            for (int ni = 0; ni < 4; ++ni)
                op[ni * 16 + col] = acc[mi][ni][reg];
        }
    }
}

extern "C" void kernel_launch(void* const* d_in, const int* in_sizes, int n_in,
                              void* d_out, int out_size, void* d_ws, size_t ws_size,
                              hipStream_t stream) {
    const float* x  = (const float*)d_in[0];
    const float* Wh = (const float*)d_in[1];
    const float* Mh = (const float*)d_in[2];
    float* out = (float*)d_out;
    uint32_t* Af = (uint32_t*)d_ws;   // 147,456 B of A fragments

    nac_prep<<<36, 256, 0, stream>>>(Wh, Mh, Af);
    nac_conv<<<8192, 256, 0, stream>>>(x, Af, out);
}